// Round 2
// baseline (448.366 us; speedup 1.0000x reference)
//
#include <hip/hip_runtime.h>
#include <math.h>

#define BB 8
#define NN 1024
#define DD 64
#define EPSF 0.05f
#define MAX_ITER 100
// threshold on SUM of |du| over B*N (reference: mean < 1e-6)
// fixed-point: units of 2^-20; 8.192e-3 * 2^20 = 8589.9 -> 8590
#define ERR_FX_THRESH 8590u
// 1/(eps*ln2) and eps*ln2
#define SCALE_ 28.853900817779268f
#define EPSLN2_ 0.034657359027997264f
#define NBLK 256
#define NPERW 128   // waves per batch err counter (32 blocks x 4 waves)
// tagged-word codec: [31:25]=iter tag, [24:0]=signed fixed point, 2^-21 units
#define QSCALE 2097152.0f
#define DECE ((float)(28.853900817779268 / 2097152.0))   // SCALE_ / 2^21

typedef __attribute__((ext_vector_type(8))) short short8;
typedef __attribute__((ext_vector_type(4))) float f32x4;

static __device__ __forceinline__ float fexp2(float x) { return __builtin_amdgcn_exp2f(x); }
static __device__ __forceinline__ float flog2(float x) { return __builtin_amdgcn_logf(x); }
static __device__ __forceinline__ float bflo(unsigned u) { return __uint_as_float(u << 16); }
static __device__ __forceinline__ unsigned short bf16rne(float x) {
    unsigned u = __float_as_uint(x);
    u += 0x7fffu + ((u >> 16) & 1u);
    return (unsigned short)(u >> 16);
}
__device__ __forceinline__ float wave_sum64(float x) {
#pragma unroll
    for (int off = 1; off < 64; off <<= 1) x += __shfl_xor(x, off);
    return x;
}
static __device__ __forceinline__ float dec_exp(unsigned w) {
    int fx = ((int)(w << 7)) >> 7;
    return fexp2((float)fx * DECE);
}

// ---- metadata: tagged u (32KB) + tagged v (32KB) + cnt64[100][8] (6400B) = 71,936B
//      <= 78,336B past the two 16MB matrices (R3-proven bound) ----
// cnt64[t*8+b]: high32 = wave-arrival count for u-phase t of batch b,
//               low32  = fixed-point err sum (2^-20 units, per-wave ceil)

// ---------------- fused normalize + cost + exp via MFMA (verbatim R1) ----------------
__global__ __launch_bounds__(256) void cost_kernel(const float* __restrict__ q,
                                                   const float* __restrict__ k,
                                                   unsigned short* __restrict__ M,
                                                   unsigned short* __restrict__ MT) {
    __shared__ __align__(16) float Qs[64][65];
    __shared__ __align__(16) float Ks[64][65];
    __shared__ float qin[64];
    __shared__ float kin[64];
    __shared__ __align__(16) unsigned short Qb[64][72];   // pitch 72: 2-way conflict = free
    __shared__ __align__(16) unsigned short Kb[64][72];
    int b = blockIdx.z;
    int i0 = blockIdx.y * 64, j0 = blockIdx.x * 64;
    const float* Qp = q + ((size_t)b * NN + i0) * DD;
    const float* Kp = k + ((size_t)b * NN + j0) * DD;
    int tid = threadIdx.x;
#pragma unroll
    for (int kk = 0; kk < 4; ++kk) {
        int c = tid + 256 * kk;
        int row = c >> 4;
        int c4 = c & 15;
        float4 qv = ((const float4*)(Qp + row * DD))[c4];
        Qs[row][c4 * 4 + 0] = qv.x; Qs[row][c4 * 4 + 1] = qv.y;
        Qs[row][c4 * 4 + 2] = qv.z; Qs[row][c4 * 4 + 3] = qv.w;
        float4 kv = ((const float4*)(Kp + row * DD))[c4];
        Ks[row][c4 * 4 + 0] = kv.x; Ks[row][c4 * 4 + 1] = kv.y;
        Ks[row][c4 * 4 + 2] = kv.z; Ks[row][c4 * 4 + 3] = kv.w;
    }
    __syncthreads();
    if (tid < 64) {
        float ss = 0.f;
#pragma unroll 16
        for (int d = 0; d < 64; ++d) ss += Qs[tid][d] * Qs[tid][d];
        qin[tid] = 1.0f / fmaxf(sqrtf(ss), 1e-12f);
    } else if (tid < 128) {
        int r = tid - 64;
        float ss = 0.f;
#pragma unroll 16
        for (int d = 0; d < 64; ++d) ss += Ks[r][d] * Ks[r][d];
        kin[r] = 1.0f / fmaxf(sqrtf(ss), 1e-12f);
    }
    __syncthreads();
    {
        int row = tid >> 2, d0 = (tid & 3) * 16;
        float qs = qin[row], ks = kin[row];
#pragma unroll
        for (int p = 0; p < 4; ++p) {
            int d = d0 + p * 4;
            uint2 t;
            t.x = (unsigned)bf16rne(Qs[row][d + 0] * qs) | ((unsigned)bf16rne(Qs[row][d + 1] * qs) << 16);
            t.y = (unsigned)bf16rne(Qs[row][d + 2] * qs) | ((unsigned)bf16rne(Qs[row][d + 3] * qs) << 16);
            *(uint2*)&Qb[row][d] = t;
            t.x = (unsigned)bf16rne(Ks[row][d + 0] * ks) | ((unsigned)bf16rne(Ks[row][d + 1] * ks) << 16);
            t.y = (unsigned)bf16rne(Ks[row][d + 2] * ks) | ((unsigned)bf16rne(Ks[row][d + 3] * ks) << 16);
            *(uint2*)&Kb[row][d] = t;
        }
    }
    __syncthreads();
    // Qs dead from here: alias the 64x72-short exp-tile staging buffer onto it
    unsigned short* Ms = (unsigned short*)&Qs[0][0];
    int w = tid >> 6, lane = tid & 63;
    int m = lane & 15, qq = lane >> 4;
    int rloc = w * 16;
    short8 a0 = *(const short8*)&Qb[rloc + m][qq * 8];
    short8 a1 = *(const short8*)&Qb[rloc + m][qq * 8 + 32];
    f32x4 acc[4];
#pragma unroll
    for (int nt = 0; nt < 4; ++nt) {
        short8 b0 = *(const short8*)&Kb[nt * 16 + m][qq * 8];
        short8 b1 = *(const short8*)&Kb[nt * 16 + m][qq * 8 + 32];
        f32x4 z = {0.f, 0.f, 0.f, 0.f};
        z = __builtin_amdgcn_mfma_f32_16x16x32_bf16(a0, b0, z, 0, 0, 0);
        acc[nt] = __builtin_amdgcn_mfma_f32_16x16x32_bf16(a1, b1, z, 0, 0, 0);
    }
#pragma unroll
    for (int nt = 0; nt < 4; ++nt) {
        int gj = j0 + nt * 16 + m;
        unsigned short us[4];
#pragma unroll
        for (int r = 0; r < 4; ++r)
            us[r] = bf16rne(fexp2((acc[nt][r] - 1.0f) * SCALE_));
#pragma unroll
        for (int r = 0; r < 4; ++r)
            Ms[(rloc + qq * 4 + r) * 72 + nt * 16 + m] = us[r];
        uint2 t;
        t.x = (unsigned)us[0] | ((unsigned)us[1] << 16);
        t.y = (unsigned)us[2] | ((unsigned)us[3] << 16);
        *(uint2*)(MT + ((size_t)b << 20) + ((size_t)gj << 10) + i0 + rloc + qq * 4) = t;
    }
    __syncthreads();
    // coalesced M write: 64 rows x 128B, 8 lanes per row, uint4 each (2 per thread)
#pragma unroll
    for (int s = 0; s < 2; ++s) {
        int idx = tid + 256 * s;
        int row = idx >> 3, seg = idx & 7;
        *(uint4*)(M + ((size_t)b << 20) + ((size_t)(i0 + row) << 10) + j0 + seg * 8) =
            *(const uint4*)&Ms[row * 72 + seg * 8];
    }
}

// ---------------- persistent Sinkhorn — tag-sync (barrier-free) ----------------
// Protocol: each u/v entry carries its iteration tag in the same 32-bit word
// (single-copy atomic) -> producers fire-and-forget, consumers poll the data
// itself. Only wave0 of each block polls globally; it republishes exp2(val*S)
// via LDS + release flag for waves 1-3. Err counters are fire-and-forget adds;
// the break for iter t-1 is evaluated at end of iter t (one extra converged
// iteration, effect ~1e-6 << bf16 noise; never breaks earlier than reference).
#define ACC8(U4, base)                                              \
    s0 = fmaf(bflo(U4.x), wrg[base + 0], s0);                       \
    s1 = fmaf(__uint_as_float(U4.x), wrg[base + 1], s1);            \
    s0 = fmaf(bflo(U4.y), wrg[base + 2], s0);                       \
    s1 = fmaf(__uint_as_float(U4.y), wrg[base + 3], s1);            \
    s0 = fmaf(bflo(U4.z), wrg[base + 4], s0);                       \
    s1 = fmaf(__uint_as_float(U4.z), wrg[base + 5], s1);            \
    s0 = fmaf(bflo(U4.w), wrg[base + 6], s0);                       \
    s1 = fmaf(__uint_as_float(U4.w), wrg[base + 7], s1);

__global__ __launch_bounds__(256, 1) void sink_coop(const unsigned short* __restrict__ M,
                                                    const unsigned short* __restrict__ MT,
                                                    unsigned* __restrict__ ut,
                                                    unsigned* __restrict__ vt,
                                                    unsigned long long* __restrict__ cnt64,
                                                    float eln) {
    __shared__ __align__(16) float bufU[1280];   // pitch-20 padded, 64 lanes x 16
    __shared__ __align__(16) float bufV[1280];
    __shared__ int flagU, flagV;
    int tid = threadIdx.x;
    int w = tid >> 6, lane = tid & 63;
    int b = blockIdx.x & 7;
    int slice = blockIdx.x >> 3;          // 0..31
    int rbase = slice * 32 + w * 8;       // wave's first local row
    const unsigned short* Mb  = M  + ((size_t)b << 20);
    const unsigned short* MTb = MT + ((size_t)b << 20);
    unsigned* ub = ut + (b << 10);
    unsigned* vb = vt + (b << 10);
    const unsigned* vp = vb + lane * 16;   // wave0: lane's 16 v entries
    const unsigned* up = ub + lane * 16;

    if (tid == 0) { flagU = 0; flagV = 0; }

    // ---- preload this wave's 8 M-rows + 8 MT-rows into registers ----
    uint4 mA[8], mB[8], nA[8], nB[8];
#pragma unroll
    for (int r = 0; r < 8; ++r) {
        const uint4* rp = (const uint4*)(Mb + ((size_t)(rbase + r) << 10));
        mA[r] = rp[lane * 2];
        mB[r] = rp[lane * 2 + 1];
        const uint4* tp = (const uint4*)(MTb + ((size_t)(rbase + r) << 10));
        nA[r] = tp[lane * 2];
        nB[r] = tp[lane * 2 + 1];
    }
    __syncthreads();   // flag init visible (one-time)

    float uprev[8];
#pragma unroll
    for (int r = 0; r < 8; ++r) uprev[r] = 0.f;

    for (int t = 0; t < MAX_ITER; ++t) {
        unsigned tgv = (unsigned)t;        // v written in iter t-1 carries tag t
        unsigned tgu = (unsigned)(t + 1);  // u/v written this iter carry tag t+1
        // ---------- u phase ----------
        float wrg[16];
        if (w == 0) {
            unsigned wv[16];
            for (;;) {
                unsigned bad = 0;
#pragma unroll
                for (int i = 0; i < 16; ++i)
                    wv[i] = __hip_atomic_load(vp + i, __ATOMIC_RELAXED, __HIP_MEMORY_SCOPE_AGENT);
#pragma unroll
                for (int i = 0; i < 16; ++i) bad |= (wv[i] >> 25) ^ tgv;
                if (!bad) break;
                __builtin_amdgcn_s_sleep(1);
            }
#pragma unroll
            for (int i = 0; i < 4; ++i) {
                float4 f;
                f.x = dec_exp(wv[i * 4 + 0]); f.y = dec_exp(wv[i * 4 + 1]);
                f.z = dec_exp(wv[i * 4 + 2]); f.w = dec_exp(wv[i * 4 + 3]);
                *(float4*)&bufU[lane * 20 + i * 4] = f;
                wrg[i * 4 + 0] = f.x; wrg[i * 4 + 1] = f.y;
                wrg[i * 4 + 2] = f.z; wrg[i * 4 + 3] = f.w;
            }
            if (lane == 0)
                __hip_atomic_store(&flagU, t + 1, __ATOMIC_RELEASE, __HIP_MEMORY_SCOPE_WORKGROUP);
        } else {
            while (__hip_atomic_load(&flagU, __ATOMIC_ACQUIRE, __HIP_MEMORY_SCOPE_WORKGROUP) < t + 1) {}
#pragma unroll
            for (int i = 0; i < 4; ++i) {
                float4 f = *(const float4*)&bufU[lane * 20 + i * 4];
                wrg[i * 4 + 0] = f.x; wrg[i * 4 + 1] = f.y;
                wrg[i * 4 + 2] = f.z; wrg[i * 4 + 3] = f.w;
            }
        }
        float del = 0.f;
#pragma unroll
        for (int rr = 0; rr < 8; ++rr) {
            float s0 = 0.f, s1 = 0.f;
            ACC8(mA[rr], 0)
            ACC8(mB[rr], 8)
            float s = wave_sum64(s0 + s1);
            float un = eln - EPSLN2_ * flog2(s);
            del += fabsf(un - uprev[rr]);
            uprev[rr] = un;
            if (lane == 0) {
                float uq = fminf(fmaxf(un, -7.99f), 7.99f);
                int fx = (int)rintf(uq * QSCALE);
                unsigned word = (tgu << 25) | ((unsigned)fx & 0x1FFFFFFu);
                __hip_atomic_store(ub + rbase + rr, word, __ATOMIC_RELAXED, __HIP_MEMORY_SCOPE_AGENT);
            }
        }
        if (lane == 0) {
            // per-wave ceil(2^-20 units), saturated so 128 waves can't overflow 32 bits
            unsigned dfx = (unsigned)fminf(del * 1048576.0f, 1.5e7f) + 1u;
            __hip_atomic_fetch_add(cnt64 + (size_t)t * 8 + b,
                                   (1ULL << 32) | (unsigned long long)dfx,
                                   __ATOMIC_RELAXED, __HIP_MEMORY_SCOPE_AGENT);
        }
        // early-issue break-counter loads for iter t-1 (off critical path)
        unsigned long long e[8];
        if (t) {
#pragma unroll
            for (int i = 0; i < 8; ++i)
                e[i] = __hip_atomic_load(cnt64 + (size_t)(t - 1) * 8 + i,
                                         __ATOMIC_RELAXED, __HIP_MEMORY_SCOPE_AGENT);
        }
        // ---------- v phase ----------
        if (w == 0) {
            unsigned wu[16];
            for (;;) {
                unsigned bad = 0;
#pragma unroll
                for (int i = 0; i < 16; ++i)
                    wu[i] = __hip_atomic_load(up + i, __ATOMIC_RELAXED, __HIP_MEMORY_SCOPE_AGENT);
#pragma unroll
                for (int i = 0; i < 16; ++i) bad |= (wu[i] >> 25) ^ tgu;
                if (!bad) break;
                __builtin_amdgcn_s_sleep(1);
            }
#pragma unroll
            for (int i = 0; i < 4; ++i) {
                float4 f;
                f.x = dec_exp(wu[i * 4 + 0]); f.y = dec_exp(wu[i * 4 + 1]);
                f.z = dec_exp(wu[i * 4 + 2]); f.w = dec_exp(wu[i * 4 + 3]);
                *(float4*)&bufV[lane * 20 + i * 4] = f;
                wrg[i * 4 + 0] = f.x; wrg[i * 4 + 1] = f.y;
                wrg[i * 4 + 2] = f.z; wrg[i * 4 + 3] = f.w;
            }
            if (lane == 0)
                __hip_atomic_store(&flagV, t + 1, __ATOMIC_RELEASE, __HIP_MEMORY_SCOPE_WORKGROUP);
        } else {
            while (__hip_atomic_load(&flagV, __ATOMIC_ACQUIRE, __HIP_MEMORY_SCOPE_WORKGROUP) < t + 1) {}
#pragma unroll
            for (int i = 0; i < 4; ++i) {
                float4 f = *(const float4*)&bufV[lane * 20 + i * 4];
                wrg[i * 4 + 0] = f.x; wrg[i * 4 + 1] = f.y;
                wrg[i * 4 + 2] = f.z; wrg[i * 4 + 3] = f.w;
            }
        }
#pragma unroll
        for (int rr = 0; rr < 8; ++rr) {
            float s0 = 0.f, s1 = 0.f;
            ACC8(nA[rr], 0)
            ACC8(nB[rr], 8)
            float s = wave_sum64(s0 + s1);
            float vn = eln - EPSLN2_ * flog2(s);
            if (lane == 0) {
                float vq = fminf(fmaxf(vn, -7.99f), 7.99f);
                int fx = (int)rintf(vq * QSCALE);
                unsigned word = (tgu << 25) | ((unsigned)fx & 0x1FFFFFFu);
                __hip_atomic_store(vb + rbase + rr, word, __ATOMIC_RELAXED, __HIP_MEMORY_SCOPE_AGENT);
            }
        }
        // ---------- deferred break (iter t-1's global err) ----------
        if (t) {
            unsigned long long s = 0;
            for (;;) {
                unsigned mn = 0xffffffffu;
                s = 0;
#pragma unroll
                for (int i = 0; i < 8; ++i) {
                    unsigned c = (unsigned)(e[i] >> 32);
                    if (c < mn) mn = c;
                    s += (unsigned long long)(unsigned)(e[i] & 0xffffffffULL);
                }
                if (mn >= NPERW) break;   // counters complete (virtually always first try)
                __builtin_amdgcn_s_sleep(1);
#pragma unroll
                for (int i = 0; i < 8; ++i)
                    e[i] = __hip_atomic_load(cnt64 + (size_t)(t - 1) * 8 + i,
                                             __ATOMIC_RELAXED, __HIP_MEMORY_SCOPE_AGENT);
            }
            if (s < (unsigned long long)ERR_FX_THRESH) break;
        }
    }
}

// ---------------- WT precompute: WT[b][d][j] = bf16( exp2(v_j*S) * V[b][j][d] ) ----------------
__global__ __launch_bounds__(256) void wt_kernel(const float* __restrict__ V,
                                                 const unsigned* __restrict__ vt,
                                                 unsigned short* __restrict__ WT) {
    __shared__ __align__(16) float Vs[64][65];
    __shared__ float wj[64];
    int b = blockIdx.x & 7, jt = blockIdx.x >> 3;
    int j0 = jt * 64;
    int tid = threadIdx.x;
    const float* Vb = V + ((size_t)b << 16) + ((size_t)j0 << 6);
#pragma unroll
    for (int c = 0; c < 4; ++c) {
        int idx = tid + 256 * c;
        int row = idx >> 4, c4 = idx & 15;
        float4 x = ((const float4*)(Vb + row * 64))[c4];
        Vs[row][c4 * 4 + 0] = x.x; Vs[row][c4 * 4 + 1] = x.y;
        Vs[row][c4 * 4 + 2] = x.z; Vs[row][c4 * 4 + 3] = x.w;
    }
    if (tid < 64) wj[tid] = dec_exp(vt[(b << 10) + j0 + tid]);
    __syncthreads();
    int d = tid >> 2, qd = tid & 3;
    unsigned pk[8];
#pragma unroll
    for (int p = 0; p < 8; ++p) {
        int j = qd * 16 + p * 2;
        unsigned lo = bf16rne(Vs[j][d] * wj[j]);
        unsigned hi = bf16rne(Vs[j + 1][d] * wj[j + 1]);
        pk[p] = lo | (hi << 16);
    }
    unsigned short* dst = WT + ((size_t)b << 16) + ((size_t)d << 10) + j0 + qd * 16;
    ((uint4*)dst)[0] = make_uint4(pk[0], pk[1], pk[2], pk[3]);
    ((uint4*)dst)[1] = make_uint4(pk[4], pk[5], pk[6], pk[7]);
}

// ---------------- MFMA epilogue: out = diag(a) * (M @ W) + V ----------------
__global__ __launch_bounds__(256) void gemm_final(const unsigned short* __restrict__ M,
                                                  const unsigned short* __restrict__ WT,
                                                  const unsigned* __restrict__ ut,
                                                  const float* __restrict__ V,
                                                  float* __restrict__ out) {
    __shared__ float sa[32];
    int tid = threadIdx.x;
    int w = tid >> 6, lane = tid & 63;
    int b = blockIdx.x & 7, mt = blockIdx.x >> 3;
    if (tid < 32) sa[tid] = dec_exp(ut[(b << 10) + mt * 32 + tid]);
    __syncthreads();
    int m = lane & 15, q = lane >> 4;
    int rloc = (w & 1) * 16;
    int nbase = (w >> 1) * 32;
    const unsigned short* Ma = M + ((size_t)b << 20) + ((size_t)(mt * 32 + rloc + m) << 10) + q * 8;
    const unsigned short* W0 = WT + ((size_t)b << 16) + ((size_t)(nbase + m) << 10) + q * 8;
    const unsigned short* W1 = W0 + (16 << 10);
    f32x4 acc0 = {0.f, 0.f, 0.f, 0.f}, acc1 = {0.f, 0.f, 0.f, 0.f};
#pragma unroll 4
    for (int k0 = 0; k0 < NN; k0 += 32) {
        short8 af = *(const short8*)(Ma + k0);
        short8 b0 = *(const short8*)(W0 + k0);
        short8 b1 = *(const short8*)(W1 + k0);
        acc0 = __builtin_amdgcn_mfma_f32_16x16x32_bf16(af, b0, acc0, 0, 0, 0);
        acc1 = __builtin_amdgcn_mfma_f32_16x16x32_bf16(af, b1, acc1, 0, 0, 0);
    }
#pragma unroll
    for (int r = 0; r < 4; ++r) {
        int lrow = rloc + q * 4 + r;
        int gm = mt * 32 + lrow;
        float a = sa[lrow];
        size_t base = (((size_t)b << 10) + gm) * DD;
        int n0 = nbase + m;
        out[base + n0]      = fmaf(a, acc0[r], V[base + n0]);
        out[base + n0 + 16] = fmaf(a, acc1[r], V[base + n0 + 16]);
    }
}

extern "C" void kernel_launch(void* const* d_in, const int* in_sizes, int n_in,
                              void* d_out, int out_size, void* d_ws, size_t ws_size,
                              hipStream_t stream) {
    const float* q = (const float*)d_in[0];
    const float* k = (const float*)d_in[1];
    const float* V = (const float*)d_in[2];
    float* out = (float*)d_out;

    char* ws = (char*)d_ws;
    const size_t MB16 = (size_t)BB * NN * NN * sizeof(unsigned short);   // 16 MB
    unsigned short* M  = (unsigned short*)ws;
    unsigned short* MT = (unsigned short*)(ws + MB16);
    unsigned short* WT = MT;                  // MT is dead after sink; reuse (1 MB)
    unsigned* ut = (unsigned*)(ws + 2 * MB16);             // 8192 tagged words (32 KB)
    unsigned* vt = ut + BB * NN;                           // 8192 tagged words (32 KB)
    unsigned long long* cnt64 = (unsigned long long*)(vt + BB * NN);   // 800 u64 = 6,400 B

    // ut, vt, cnt64 contiguous: 65,536 + 6,400 = 71,936 B (<= 78,336 B proven bound)
    size_t zbytes = (size_t)(2 * BB * NN) * 4 + 800 * 8;
    hipMemsetAsync(ut, 0, zbytes, stream);

    cost_kernel<<<dim3(16, 16, 8), 256, 0, stream>>>(q, k, M, MT);

    float eln = EPSF * logf(1.0f / NN + 1e-8f);
    // REGULAR launch: tag-sync is hand-rolled, co-residency is de-facto guaranteed at
    // 256 blocks / 256 CUs. Failure mode if placement ever splits: visible hang,
    // not silent corruption.
    sink_coop<<<dim3(NBLK), dim3(256), 0, stream>>>(M, MT, ut, vt, cnt64, eln);

    wt_kernel<<<128, 256, 0, stream>>>(V, vt, WT);
    gemm_final<<<256, 256, 0, stream>>>(M, WT, ut, V, out);
}

// Round 3
// 233.771 us; speedup vs baseline: 1.9180x; 1.9180x over previous
//
#include <hip/hip_runtime.h>
#include <math.h>

#define BB 8
#define NN 1024
#define DD 64
#define EPSF 0.05f
#define MAX_ITER 100
// threshold on SUM of |du| over B*N (reference: mean < 1e-6)
// fixed-point: units of 2^-20; 8.192e-3 * 2^20 = 8589.9 -> 8590
#define ERR_FX_THRESH 8590u
// 1/(eps*ln2) and eps*ln2
#define SCALE_ 28.853900817779268f
#define EPSLN2_ 0.034657359027997264f
#define NBLK 256
#define NPER 32   // blocks per batch barrier

typedef __attribute__((ext_vector_type(8))) short short8;
typedef __attribute__((ext_vector_type(4))) float f32x4;

static __device__ __forceinline__ float fexp2(float x) { return __builtin_amdgcn_exp2f(x); }
static __device__ __forceinline__ float flog2(float x) { return __builtin_amdgcn_logf(x); }
static __device__ __forceinline__ float bflo(unsigned u) { return __uint_as_float(u << 16); }
static __device__ __forceinline__ unsigned short bf16rne(float x) {
    unsigned u = __float_as_uint(x);
    u += 0x7fffu + ((u >> 16) & 1u);
    return (unsigned short)(u >> 16);
}
__device__ __forceinline__ float wave_sum64(float x) {
#pragma unroll
    for (int off = 1; off < 64; off <<= 1) x += __shfl_xor(x, off);
    return x;
}

// ---- metadata: u/v floats (64KB) + cnt64 (12.8KB) = 78,336B past the two 16MB
//      matrices (R3-proven bound). PER-BATCH counter stripes (1600B apart ->
//      distinct, XCD-local lines; R2 proved sharing one line across batches is a
//      4x remote-atomic disaster) ----
// cnt64[b*200+p]: high32 = block-arrival count for phase p of batch b,
//                 low32  = fixed-point err sum (u-phases, 2^-20 units, per-wave ceil)
#define CNT64IDX(p, b) ((b) * 200 + (p))

// ---------------- fused normalize + cost + exp via MFMA (verbatim R1-proven) ----------------
__global__ __launch_bounds__(256) void cost_kernel(const float* __restrict__ q,
                                                   const float* __restrict__ k,
                                                   unsigned short* __restrict__ M,
                                                   unsigned short* __restrict__ MT) {
    __shared__ __align__(16) float Qs[64][65];
    __shared__ __align__(16) float Ks[64][65];
    __shared__ float qin[64];
    __shared__ float kin[64];
    __shared__ __align__(16) unsigned short Qb[64][72];   // pitch 72: 2-way conflict = free
    __shared__ __align__(16) unsigned short Kb[64][72];
    int b = blockIdx.z;
    int i0 = blockIdx.y * 64, j0 = blockIdx.x * 64;
    const float* Qp = q + ((size_t)b * NN + i0) * DD;
    const float* Kp = k + ((size_t)b * NN + j0) * DD;
    int tid = threadIdx.x;
#pragma unroll
    for (int kk = 0; kk < 4; ++kk) {
        int c = tid + 256 * kk;
        int row = c >> 4;
        int c4 = c & 15;
        float4 qv = ((const float4*)(Qp + row * DD))[c4];
        Qs[row][c4 * 4 + 0] = qv.x; Qs[row][c4 * 4 + 1] = qv.y;
        Qs[row][c4 * 4 + 2] = qv.z; Qs[row][c4 * 4 + 3] = qv.w;
        float4 kv = ((const float4*)(Kp + row * DD))[c4];
        Ks[row][c4 * 4 + 0] = kv.x; Ks[row][c4 * 4 + 1] = kv.y;
        Ks[row][c4 * 4 + 2] = kv.z; Ks[row][c4 * 4 + 3] = kv.w;
    }
    __syncthreads();
    if (tid < 64) {
        float ss = 0.f;
#pragma unroll 16
        for (int d = 0; d < 64; ++d) ss += Qs[tid][d] * Qs[tid][d];
        qin[tid] = 1.0f / fmaxf(sqrtf(ss), 1e-12f);
    } else if (tid < 128) {
        int r = tid - 64;
        float ss = 0.f;
#pragma unroll 16
        for (int d = 0; d < 64; ++d) ss += Ks[r][d] * Ks[r][d];
        kin[r] = 1.0f / fmaxf(sqrtf(ss), 1e-12f);
    }
    __syncthreads();
    {
        int row = tid >> 2, d0 = (tid & 3) * 16;
        float qs = qin[row], ks = kin[row];
#pragma unroll
        for (int p = 0; p < 4; ++p) {
            int d = d0 + p * 4;
            uint2 t;
            t.x = (unsigned)bf16rne(Qs[row][d + 0] * qs) | ((unsigned)bf16rne(Qs[row][d + 1] * qs) << 16);
            t.y = (unsigned)bf16rne(Qs[row][d + 2] * qs) | ((unsigned)bf16rne(Qs[row][d + 3] * qs) << 16);
            *(uint2*)&Qb[row][d] = t;
            t.x = (unsigned)bf16rne(Ks[row][d + 0] * ks) | ((unsigned)bf16rne(Ks[row][d + 1] * ks) << 16);
            t.y = (unsigned)bf16rne(Ks[row][d + 2] * ks) | ((unsigned)bf16rne(Ks[row][d + 3] * ks) << 16);
            *(uint2*)&Kb[row][d] = t;
        }
    }
    __syncthreads();
    // Qs dead from here: alias the 64x72-short exp-tile staging buffer onto it
    unsigned short* Ms = (unsigned short*)&Qs[0][0];
    int w = tid >> 6, lane = tid & 63;
    int m = lane & 15, qq = lane >> 4;
    int rloc = w * 16;
    short8 a0 = *(const short8*)&Qb[rloc + m][qq * 8];
    short8 a1 = *(const short8*)&Qb[rloc + m][qq * 8 + 32];
    f32x4 acc[4];
#pragma unroll
    for (int nt = 0; nt < 4; ++nt) {
        short8 b0 = *(const short8*)&Kb[nt * 16 + m][qq * 8];
        short8 b1 = *(const short8*)&Kb[nt * 16 + m][qq * 8 + 32];
        f32x4 z = {0.f, 0.f, 0.f, 0.f};
        z = __builtin_amdgcn_mfma_f32_16x16x32_bf16(a0, b0, z, 0, 0, 0);
        acc[nt] = __builtin_amdgcn_mfma_f32_16x16x32_bf16(a1, b1, z, 0, 0, 0);
    }
#pragma unroll
    for (int nt = 0; nt < 4; ++nt) {
        int gj = j0 + nt * 16 + m;
        unsigned short us[4];
#pragma unroll
        for (int r = 0; r < 4; ++r)
            us[r] = bf16rne(fexp2((acc[nt][r] - 1.0f) * SCALE_));
#pragma unroll
        for (int r = 0; r < 4; ++r)
            Ms[(rloc + qq * 4 + r) * 72 + nt * 16 + m] = us[r];
        uint2 t;
        t.x = (unsigned)us[0] | ((unsigned)us[1] << 16);
        t.y = (unsigned)us[2] | ((unsigned)us[3] << 16);
        *(uint2*)(MT + ((size_t)b << 20) + ((size_t)gj << 10) + i0 + rloc + qq * 4) = t;
    }
    __syncthreads();
    // coalesced M write: 64 rows x 128B, 8 lanes per row, uint4 each (2 per thread)
#pragma unroll
    for (int s = 0; s < 2; ++s) {
        int idx = tid + 256 * s;
        int row = idx >> 3, seg = idx & 7;
        *(uint4*)(M + ((size_t)b << 20) + ((size_t)(i0 + row) << 10) + j0 + seg * 8) =
            *(const uint4*)&Ms[row * 72 + seg * 8];
    }
}

// ---------------- persistent Sinkhorn — R1 protocol, wave-autonomous arrival ----------------
// Per phase: LDS exchange (1 syncthreads) -> compute -> per-wave vmcnt(0) drain ->
// LDS del-add + LDS arrival (ds_add_rtn); the wave seeing old==3 fires the ONE
// per-block fused global fetch_add (count|err) -> ALL lanes poll the global
// counter (wave-uniform address = 1 L2 request/wave). No post-store or
// post-poll __syncthreads. Counter layout & rare-path cross-batch break = R1.
#define ACC8(U4, base)                                              \
    s0 = fmaf(bflo(U4.x), wrg[base + 0], s0);                       \
    s1 = fmaf(__uint_as_float(U4.x), wrg[base + 1], s1);            \
    s0 = fmaf(bflo(U4.y), wrg[base + 2], s0);                       \
    s1 = fmaf(__uint_as_float(U4.y), wrg[base + 3], s1);            \
    s0 = fmaf(bflo(U4.z), wrg[base + 4], s0);                       \
    s1 = fmaf(__uint_as_float(U4.z), wrg[base + 5], s1);            \
    s0 = fmaf(bflo(U4.w), wrg[base + 6], s0);                       \
    s1 = fmaf(__uint_as_float(U4.w), wrg[base + 7], s1);

__global__ __launch_bounds__(256, 1) void sink_coop(const unsigned short* __restrict__ M,
                                                    const unsigned short* __restrict__ MT,
                                                    float* __restrict__ u,
                                                    float* __restrict__ v,
                                                    unsigned long long* __restrict__ cnt64,
                                                    float eln) {
    __shared__ __align__(16) float bufU[1280];   // pitch-20 padded exchange, u phase
    __shared__ __align__(16) float bufV[1280];   // v phase
    __shared__ unsigned arr[2];                  // LDS arrival counters (u, v)
    __shared__ unsigned ldsdel;                  // fixed-point del accumulator
    int tid = threadIdx.x;
    int w = tid >> 6, lane = tid & 63;
    int b = blockIdx.x & 7;
    int slice = blockIdx.x >> 3;          // 0..31
    int rbase = slice * 32 + w * 8;       // wave's first local row
    const unsigned short* Mb  = M  + ((size_t)b << 20);
    const unsigned short* MTb = MT + ((size_t)b << 20);
    float* ub = u + (b << 10);
    float* vb = v + (b << 10);

    if (tid == 0) { arr[0] = 0u; arr[1] = 0u; ldsdel = 0u; }

    // ---- preload this wave's 8 M-rows + 8 MT-rows into registers ----
    uint4 mA[8], mB[8], nA[8], nB[8];
#pragma unroll
    for (int r = 0; r < 8; ++r) {
        const uint4* rp = (const uint4*)(Mb + ((size_t)(rbase + r) << 10));
        mA[r] = rp[lane * 2];
        mB[r] = rp[lane * 2 + 1];
        const uint4* tp = (const uint4*)(MTb + ((size_t)(rbase + r) << 10));
        nA[r] = tp[lane * 2];
        nB[r] = tp[lane * 2 + 1];
    }
    __syncthreads();   // arr/ldsdel init visible (one-time)

    float uprev[8];
#pragma unroll
    for (int r = 0; r < 8; ++r) uprev[r] = 0.f;

    unsigned myerr = 0xffffffffu;   // batch err for iter t (all lanes, from u poll)

    for (int t = 0; t < MAX_ITER; ++t) {
        // ---------- u phase ----------
        {
            float4 ex;
            ex.x = fexp2(__hip_atomic_load(vb + tid * 4 + 0, __ATOMIC_RELAXED, __HIP_MEMORY_SCOPE_AGENT) * SCALE_);
            ex.y = fexp2(__hip_atomic_load(vb + tid * 4 + 1, __ATOMIC_RELAXED, __HIP_MEMORY_SCOPE_AGENT) * SCALE_);
            ex.z = fexp2(__hip_atomic_load(vb + tid * 4 + 2, __ATOMIC_RELAXED, __HIP_MEMORY_SCOPE_AGENT) * SCALE_);
            ex.w = fexp2(__hip_atomic_load(vb + tid * 4 + 3, __ATOMIC_RELAXED, __HIP_MEMORY_SCOPE_AGENT) * SCALE_);
            *(float4*)&bufU[tid * 4 + 4 * (tid >> 2)] = ex;
            __syncthreads();
            float wrg[16];
            *(float4*)&wrg[0]  = *(const float4*)&bufU[lane * 20 + 0];
            *(float4*)&wrg[4]  = *(const float4*)&bufU[lane * 20 + 4];
            *(float4*)&wrg[8]  = *(const float4*)&bufU[lane * 20 + 8];
            *(float4*)&wrg[12] = *(const float4*)&bufU[lane * 20 + 12];
            float del = 0.f;
#pragma unroll
            for (int rr = 0; rr < 8; ++rr) {
                float s0 = 0.f, s1 = 0.f;
                ACC8(mA[rr], 0)
                ACC8(mB[rr], 8)
                float s = wave_sum64(s0 + s1);
                float un = eln - EPSLN2_ * flog2(s);
                del += fabsf(un - uprev[rr]);
                uprev[rr] = un;
                if (lane == 0)
                    __hip_atomic_store(ub + rbase + rr, un, __ATOMIC_RELAXED, __HIP_MEMORY_SCOPE_AGENT);
            }
            asm volatile("s_waitcnt vmcnt(0)" ::: "memory");   // this wave's stores at L2
            unsigned long long* c = cnt64 + CNT64IDX(2 * t, b);
            if (lane == 0) {
                // per-wave ceil (2^-20 units), saturated: block sum < 6e7+4, x32 blocks < 2^31
                unsigned dfx = (unsigned)fminf(del * 1048576.0f, 1.5e7f) + 1u;
                __hip_atomic_fetch_add(&ldsdel, dfx, __ATOMIC_RELAXED, __HIP_MEMORY_SCOPE_WORKGROUP);
                unsigned old = __hip_atomic_fetch_add(&arr[0], 1u, __ATOMIC_ACQ_REL, __HIP_MEMORY_SCOPE_WORKGROUP);
                if (old == 3u) {   // last local wave: all 4 waves' stores drained
                    unsigned ds = __hip_atomic_load(&ldsdel, __ATOMIC_RELAXED, __HIP_MEMORY_SCOPE_WORKGROUP);
                    __hip_atomic_store(&ldsdel, 0u, __ATOMIC_RELAXED, __HIP_MEMORY_SCOPE_WORKGROUP);
                    __hip_atomic_store(&arr[0], 0u, __ATOMIC_RELAXED, __HIP_MEMORY_SCOPE_WORKGROUP);
                    __hip_atomic_fetch_add(c, (1ULL << 32) | (unsigned long long)ds,
                                           __ATOMIC_RELAXED, __HIP_MEMORY_SCOPE_AGENT);
                }
            }
            // all lanes poll: wave-uniform address -> one L2 request per wave
            unsigned long long tot = __hip_atomic_load(c, __ATOMIC_RELAXED, __HIP_MEMORY_SCOPE_AGENT);
            while ((unsigned)(tot >> 32) < NPER) {
                __builtin_amdgcn_s_sleep(1);
                tot = __hip_atomic_load(c, __ATOMIC_RELAXED, __HIP_MEMORY_SCOPE_AGENT);
            }
            myerr = (unsigned)tot;   // complete batch err once count==NPER
        }
        // ---------- v phase ----------
        {
            float4 ex;
            ex.x = fexp2(__hip_atomic_load(ub + tid * 4 + 0, __ATOMIC_RELAXED, __HIP_MEMORY_SCOPE_AGENT) * SCALE_);
            ex.y = fexp2(__hip_atomic_load(ub + tid * 4 + 1, __ATOMIC_RELAXED, __HIP_MEMORY_SCOPE_AGENT) * SCALE_);
            ex.z = fexp2(__hip_atomic_load(ub + tid * 4 + 2, __ATOMIC_RELAXED, __HIP_MEMORY_SCOPE_AGENT) * SCALE_);
            ex.w = fexp2(__hip_atomic_load(ub + tid * 4 + 3, __ATOMIC_RELAXED, __HIP_MEMORY_SCOPE_AGENT) * SCALE_);
            *(float4*)&bufV[tid * 4 + 4 * (tid >> 2)] = ex;
            __syncthreads();
            float wrg[16];
            *(float4*)&wrg[0]  = *(const float4*)&bufV[lane * 20 + 0];
            *(float4*)&wrg[4]  = *(const float4*)&bufV[lane * 20 + 4];
            *(float4*)&wrg[8]  = *(const float4*)&bufV[lane * 20 + 8];
            *(float4*)&wrg[12] = *(const float4*)&bufV[lane * 20 + 12];
#pragma unroll
            for (int rr = 0; rr < 8; ++rr) {
                float s0 = 0.f, s1 = 0.f;
                ACC8(nA[rr], 0)
                ACC8(nB[rr], 8)
                float s = wave_sum64(s0 + s1);
                float vn = eln - EPSLN2_ * flog2(s);
                if (lane == 0)
                    __hip_atomic_store(vb + rbase + rr, vn, __ATOMIC_RELAXED, __HIP_MEMORY_SCOPE_AGENT);
            }
            asm volatile("s_waitcnt vmcnt(0)" ::: "memory");
            unsigned long long* c = cnt64 + CNT64IDX(2 * t + 1, b);
            if (lane == 0) {
                unsigned old = __hip_atomic_fetch_add(&arr[1], 1u, __ATOMIC_ACQ_REL, __HIP_MEMORY_SCOPE_WORKGROUP);
                if (old == 3u) {
                    __hip_atomic_store(&arr[1], 0u, __ATOMIC_RELAXED, __HIP_MEMORY_SCOPE_WORKGROUP);
                    __hip_atomic_fetch_add(c, 1ULL << 32,
                                           __ATOMIC_RELAXED, __HIP_MEMORY_SCOPE_AGENT);
                }
            }
            unsigned long long tot = __hip_atomic_load(c, __ATOMIC_RELAXED, __HIP_MEMORY_SCOPE_AGENT);
            while ((unsigned)(tot >> 32) < NPER) {
                __builtin_amdgcn_s_sleep(1);
                tot = __hip_atomic_load(c, __ATOMIC_RELAXED, __HIP_MEMORY_SCOPE_AGENT);
            }
            // ---------- break check (uniform across all lanes/waves) ----------
            if (myerr < ERR_FX_THRESH) {
                // rare path: no batch can have broken before iter t (its err <= global
                // sum), so every batch's u-counter for t will reach NPER — no deadlock.
                unsigned long long s = 0;
                for (int bb = 0; bb < 8; ++bb) {
                    unsigned long long tv = __hip_atomic_load(cnt64 + CNT64IDX(2 * t, bb),
                                                              __ATOMIC_RELAXED, __HIP_MEMORY_SCOPE_AGENT);
                    while ((unsigned)(tv >> 32) < NPER) {
                        __builtin_amdgcn_s_sleep(1);
                        tv = __hip_atomic_load(cnt64 + CNT64IDX(2 * t, bb),
                                               __ATOMIC_RELAXED, __HIP_MEMORY_SCOPE_AGENT);
                    }
                    s += (unsigned long long)(unsigned)tv;
                }
                if (s < (unsigned long long)ERR_FX_THRESH) break;
            }
        }
    }
}

// ---------------- WT precompute: WT[b][d][j] = bf16( exp2(v_j*S) * V[b][j][d] ) ----------------
__global__ __launch_bounds__(256) void wt_kernel(const float* __restrict__ V,
                                                 const float* __restrict__ v,
                                                 unsigned short* __restrict__ WT) {
    __shared__ __align__(16) float Vs[64][65];
    __shared__ float wj[64];
    int b = blockIdx.x & 7, jt = blockIdx.x >> 3;
    int j0 = jt * 64;
    int tid = threadIdx.x;
    const float* Vb = V + ((size_t)b << 16) + ((size_t)j0 << 6);
#pragma unroll
    for (int c = 0; c < 4; ++c) {
        int idx = tid + 256 * c;
        int row = idx >> 4, c4 = idx & 15;
        float4 x = ((const float4*)(Vb + row * 64))[c4];
        Vs[row][c4 * 4 + 0] = x.x; Vs[row][c4 * 4 + 1] = x.y;
        Vs[row][c4 * 4 + 2] = x.z; Vs[row][c4 * 4 + 3] = x.w;
    }
    if (tid < 64) wj[tid] = fexp2(v[(b << 10) + j0 + tid] * SCALE_);
    __syncthreads();
    int d = tid >> 2, qd = tid & 3;
    unsigned pk[8];
#pragma unroll
    for (int p = 0; p < 8; ++p) {
        int j = qd * 16 + p * 2;
        unsigned lo = bf16rne(Vs[j][d] * wj[j]);
        unsigned hi = bf16rne(Vs[j + 1][d] * wj[j + 1]);
        pk[p] = lo | (hi << 16);
    }
    unsigned short* dst = WT + ((size_t)b << 16) + ((size_t)d << 10) + j0 + qd * 16;
    ((uint4*)dst)[0] = make_uint4(pk[0], pk[1], pk[2], pk[3]);
    ((uint4*)dst)[1] = make_uint4(pk[4], pk[5], pk[6], pk[7]);
}

// ---------------- MFMA epilogue: out = diag(a) * (M @ W) + V ----------------
__global__ __launch_bounds__(256) void gemm_final(const unsigned short* __restrict__ M,
                                                  const unsigned short* __restrict__ WT,
                                                  const float* __restrict__ u,
                                                  const float* __restrict__ V,
                                                  float* __restrict__ out) {
    __shared__ float sa[32];
    int tid = threadIdx.x;
    int w = tid >> 6, lane = tid & 63;
    int b = blockIdx.x & 7, mt = blockIdx.x >> 3;
    if (tid < 32) sa[tid] = fexp2(u[(b << 10) + mt * 32 + tid] * SCALE_);
    __syncthreads();
    int m = lane & 15, q = lane >> 4;
    int rloc = (w & 1) * 16;
    int nbase = (w >> 1) * 32;
    const unsigned short* Ma = M + ((size_t)b << 20) + ((size_t)(mt * 32 + rloc + m) << 10) + q * 8;
    const unsigned short* W0 = WT + ((size_t)b << 16) + ((size_t)(nbase + m) << 10) + q * 8;
    const unsigned short* W1 = W0 + (16 << 10);
    f32x4 acc0 = {0.f, 0.f, 0.f, 0.f}, acc1 = {0.f, 0.f, 0.f, 0.f};
#pragma unroll 4
    for (int k0 = 0; k0 < NN; k0 += 32) {
        short8 af = *(const short8*)(Ma + k0);
        short8 b0 = *(const short8*)(W0 + k0);
        short8 b1 = *(const short8*)(W1 + k0);
        acc0 = __builtin_amdgcn_mfma_f32_16x16x32_bf16(af, b0, acc0, 0, 0, 0);
        acc1 = __builtin_amdgcn_mfma_f32_16x16x32_bf16(af, b1, acc1, 0, 0, 0);
    }
#pragma unroll
    for (int r = 0; r < 4; ++r) {
        int lrow = rloc + q * 4 + r;
        int gm = mt * 32 + lrow;
        float a = sa[lrow];
        size_t base = (((size_t)b << 10) + gm) * DD;
        int n0 = nbase + m;
        out[base + n0]      = fmaf(a, acc0[r], V[base + n0]);
        out[base + n0 + 16] = fmaf(a, acc1[r], V[base + n0 + 16]);
    }
}

extern "C" void kernel_launch(void* const* d_in, const int* in_sizes, int n_in,
                              void* d_out, int out_size, void* d_ws, size_t ws_size,
                              hipStream_t stream) {
    const float* q = (const float*)d_in[0];
    const float* k = (const float*)d_in[1];
    const float* V = (const float*)d_in[2];
    float* out = (float*)d_out;

    char* ws = (char*)d_ws;
    const size_t MB16 = (size_t)BB * NN * NN * sizeof(unsigned short);   // 16 MB
    unsigned short* M  = (unsigned short*)ws;
    unsigned short* MT = (unsigned short*)(ws + MB16);
    unsigned short* WT = MT;                  // MT is dead after sink; reuse (1 MB)
    float* u   = (float*)(ws + 2 * MB16);
    float* v   = u + BB * NN;                               // u+v = 64 KiB
    unsigned long long* cnt64 = (unsigned long long*)(v + BB * NN);   // 1600 u64 = 12,800 B

    // u, v, cnt64 contiguous: 65,536 + 12,800 = 78,336 B (exactly the R3-proven bound)
    size_t zbytes = (size_t)(2 * BB * NN) * 4 + 1600 * 8;
    hipMemsetAsync(u, 0, zbytes, stream);

    cost_kernel<<<dim3(16, 16, 8), 256, 0, stream>>>(q, k, M, MT);

    float eln = EPSF * logf(1.0f / NN + 1e-8f);
    // REGULAR launch: barrier is hand-rolled, co-residency is de-facto guaranteed at
    // 256 blocks / 256 CUs (128 VGPR, ~10.5KB LDS). Failure mode if placement ever
    // splits: visible hang, not silent corruption.
    sink_coop<<<dim3(NBLK), dim3(256), 0, stream>>>(M, MT, u, v, cnt64, eln);

    wt_kernel<<<128, 256, 0, stream>>>(V, v, WT);
    gemm_final<<<256, 256, 0, stream>>>(M, WT, u, V, out);
}

// Round 4
// 185.893 us; speedup vs baseline: 2.4120x; 1.2576x over previous
//
#include <hip/hip_runtime.h>
#include <math.h>

#define BB 8
#define NN 1024
#define DD 64
#define EPSF 0.05f
#define MAX_ITER 100
// threshold on SUM of |du| over B*N (reference: mean < 1e-6)
// fixed-point: units of 2^-20; 8.192e-3 * 2^20 = 8589.9 -> 8590
#define ERR_FX_THRESH 8590u
// 1/(eps*ln2) and eps*ln2
#define SCALE_ 28.853900817779268f
#define EPSLN2_ 0.034657359027997264f
#define NBLK 256
#define NPER 32   // blocks per batch barrier

typedef __attribute__((ext_vector_type(8))) short short8;
typedef __attribute__((ext_vector_type(4))) float f32x4;

static __device__ __forceinline__ float fexp2(float x) { return __builtin_amdgcn_exp2f(x); }
static __device__ __forceinline__ float flog2(float x) { return __builtin_amdgcn_logf(x); }
static __device__ __forceinline__ float bflo(unsigned u) { return __uint_as_float(u << 16); }
static __device__ __forceinline__ unsigned short bf16rne(float x) {
    unsigned u = __float_as_uint(x);
    u += 0x7fffu + ((u >> 16) & 1u);
    return (unsigned short)(u >> 16);
}
__device__ __forceinline__ float wave_sum64(float x) {
#pragma unroll
    for (int off = 1; off < 64; off <<= 1) x += __shfl_xor(x, off);
    return x;
}

// ---- metadata: u/v floats (64KB) + cnt64 (12.8KB) = 78,336B past the two 16MB
//      matrices (R3-proven bound). PER-BATCH counter stripes (1600B apart ->
//      distinct, XCD-local lines; R2 proved sharing one line across batches is a
//      4x remote-atomic disaster; R3 proved multiplying pollers on a line is a
//      1.6x loss — tid0-only polling is load-bearing) ----
// cnt64[b*200+p]: high32 = block-arrival count for phase p of batch b,
//                 low32  = fixed-point err sum (u-phases, 2^-20 units, per-block ceil)
#define CNT64IDX(p, b) ((b) * 200 + (p))

// ---------------- fused normalize + cost + exp via MFMA ----------------
// R1-proven compute; BOTH M and MT now staged through LDS for coalesced uint4
// stores (R1 proved this for M: ~9µs; MT had the same 8B-scattered pathology).
__global__ __launch_bounds__(256) void cost_kernel(const float* __restrict__ q,
                                                   const float* __restrict__ k,
                                                   unsigned short* __restrict__ M,
                                                   unsigned short* __restrict__ MT) {
    __shared__ __align__(16) float Qs[64][65];
    __shared__ __align__(16) float Ks[64][65];
    __shared__ float qin[64];
    __shared__ float kin[64];
    __shared__ __align__(16) unsigned short Qb[64][72];   // pitch 72: 2-way conflict = free
    __shared__ __align__(16) unsigned short Kb[64][72];
    int b = blockIdx.z;
    int i0 = blockIdx.y * 64, j0 = blockIdx.x * 64;
    const float* Qp = q + ((size_t)b * NN + i0) * DD;
    const float* Kp = k + ((size_t)b * NN + j0) * DD;
    int tid = threadIdx.x;
#pragma unroll
    for (int kk = 0; kk < 4; ++kk) {
        int c = tid + 256 * kk;
        int row = c >> 4;
        int c4 = c & 15;
        float4 qv = ((const float4*)(Qp + row * DD))[c4];
        Qs[row][c4 * 4 + 0] = qv.x; Qs[row][c4 * 4 + 1] = qv.y;
        Qs[row][c4 * 4 + 2] = qv.z; Qs[row][c4 * 4 + 3] = qv.w;
        float4 kv = ((const float4*)(Kp + row * DD))[c4];
        Ks[row][c4 * 4 + 0] = kv.x; Ks[row][c4 * 4 + 1] = kv.y;
        Ks[row][c4 * 4 + 2] = kv.z; Ks[row][c4 * 4 + 3] = kv.w;
    }
    __syncthreads();
    if (tid < 64) {
        float ss = 0.f;
#pragma unroll 16
        for (int d = 0; d < 64; ++d) ss += Qs[tid][d] * Qs[tid][d];
        qin[tid] = 1.0f / fmaxf(sqrtf(ss), 1e-12f);
    } else if (tid < 128) {
        int r = tid - 64;
        float ss = 0.f;
#pragma unroll 16
        for (int d = 0; d < 64; ++d) ss += Ks[r][d] * Ks[r][d];
        kin[r] = 1.0f / fmaxf(sqrtf(ss), 1e-12f);
    }
    __syncthreads();
    {
        int row = tid >> 2, d0 = (tid & 3) * 16;
        float qs = qin[row], ks = kin[row];
#pragma unroll
        for (int p = 0; p < 4; ++p) {
            int d = d0 + p * 4;
            uint2 t;
            t.x = (unsigned)bf16rne(Qs[row][d + 0] * qs) | ((unsigned)bf16rne(Qs[row][d + 1] * qs) << 16);
            t.y = (unsigned)bf16rne(Qs[row][d + 2] * qs) | ((unsigned)bf16rne(Qs[row][d + 3] * qs) << 16);
            *(uint2*)&Qb[row][d] = t;
            t.x = (unsigned)bf16rne(Ks[row][d + 0] * ks) | ((unsigned)bf16rne(Ks[row][d + 1] * ks) << 16);
            t.y = (unsigned)bf16rne(Ks[row][d + 2] * ks) | ((unsigned)bf16rne(Ks[row][d + 3] * ks) << 16);
            *(uint2*)&Kb[row][d] = t;
        }
    }
    __syncthreads();
    // Qs and Ks are dead from here (last reads in the conversion phase above):
    // alias the M-tile and MT-tile staging buffers onto them (9216B <= 16640B each).
    unsigned short* Ms  = (unsigned short*)&Qs[0][0];   // [64 i][72] exp tile
    unsigned short* MsT = (unsigned short*)&Ks[0][0];   // [64 j][72] transposed tile
    int w = tid >> 6, lane = tid & 63;
    int m = lane & 15, qq = lane >> 4;
    int rloc = w * 16;
    short8 a0 = *(const short8*)&Qb[rloc + m][qq * 8];
    short8 a1 = *(const short8*)&Qb[rloc + m][qq * 8 + 32];
    f32x4 acc[4];
#pragma unroll
    for (int nt = 0; nt < 4; ++nt) {
        short8 b0 = *(const short8*)&Kb[nt * 16 + m][qq * 8];
        short8 b1 = *(const short8*)&Kb[nt * 16 + m][qq * 8 + 32];
        f32x4 z = {0.f, 0.f, 0.f, 0.f};
        z = __builtin_amdgcn_mfma_f32_16x16x32_bf16(a0, b0, z, 0, 0, 0);
        acc[nt] = __builtin_amdgcn_mfma_f32_16x16x32_bf16(a1, b1, z, 0, 0, 0);
    }
#pragma unroll
    for (int nt = 0; nt < 4; ++nt) {
        unsigned short us[4];
#pragma unroll
        for (int r = 0; r < 4; ++r)
            us[r] = bf16rne(fexp2((acc[nt][r] - 1.0f) * SCALE_));
        // stage M tile: rows i = rloc+qq*4+r, col j = nt*16+m (2B writes, cheap)
#pragma unroll
        for (int r = 0; r < 4; ++r)
            Ms[(rloc + qq * 4 + r) * 72 + nt * 16 + m] = us[r];
        // stage MT tile: row j = nt*16+m, cols i = rloc+qq*4..+3 (one 8B write)
        uint2 t;
        t.x = (unsigned)us[0] | ((unsigned)us[1] << 16);
        t.y = (unsigned)us[2] | ((unsigned)us[3] << 16);
        *(uint2*)&MsT[(nt * 16 + m) * 72 + rloc + qq * 4] = t;
    }
    __syncthreads();
    // coalesced stores: 64 rows x 128B each, 8 lanes per row, uint4 x2 per thread
#pragma unroll
    for (int s = 0; s < 2; ++s) {
        int idx = tid + 256 * s;
        int row = idx >> 3, seg = idx & 7;
        *(uint4*)(M + ((size_t)b << 20) + ((size_t)(i0 + row) << 10) + j0 + seg * 8) =
            *(const uint4*)&Ms[row * 72 + seg * 8];
        *(uint4*)(MT + ((size_t)b << 20) + ((size_t)(j0 + row) << 10) + i0 + seg * 8) =
            *(const uint4*)&MsT[row * 72 + seg * 8];
    }
}

// ---------------- persistent Sinkhorn (verbatim R1-proven, 87.5µs) ----------------
// Fused 64-bit barrier: ONE fetch_add publishes err AND arrives; tid0-only poll;
// break decision from the poll word; rare-path cross-batch confirm. R2/R3 proved
// every deviation (shared counter lines, deferred lockstep break, all-wave
// polling) regresses 1.6-4x — do not touch.
#define ACC8(U4, base)                                              \
    s0 = fmaf(bflo(U4.x), wrg[base + 0], s0);                       \
    s1 = fmaf(__uint_as_float(U4.x), wrg[base + 1], s1);            \
    s0 = fmaf(bflo(U4.y), wrg[base + 2], s0);                       \
    s1 = fmaf(__uint_as_float(U4.y), wrg[base + 3], s1);            \
    s0 = fmaf(bflo(U4.z), wrg[base + 4], s0);                       \
    s1 = fmaf(__uint_as_float(U4.z), wrg[base + 5], s1);            \
    s0 = fmaf(bflo(U4.w), wrg[base + 6], s0);                       \
    s1 = fmaf(__uint_as_float(U4.w), wrg[base + 7], s1);

__global__ __launch_bounds__(256, 1) void sink_coop(const unsigned short* __restrict__ M,
                                                    const unsigned short* __restrict__ MT,
                                                    float* __restrict__ u,
                                                    float* __restrict__ v,
                                                    unsigned long long* __restrict__ cnt64,
                                                    float eln) {
    __shared__ __align__(16) float sw[1280];   // pitch-20 padded
    __shared__ float sdel[4];
    __shared__ int sflag;
    int tid = threadIdx.x;
    int w = tid >> 6, lane = tid & 63;
    int b = blockIdx.x & 7;
    int slice = blockIdx.x >> 3;          // 0..31
    int rbase = slice * 32 + w * 8;       // wave's first local row
    const unsigned short* Mb  = M  + ((size_t)b << 20);
    const unsigned short* MTb = MT + ((size_t)b << 20);
    float* ub = u + (b << 10);
    float* vb = v + (b << 10);

    // ---- preload this wave's 8 M-rows + 8 MT-rows into registers ----
    uint4 mA[8], mB[8], nA[8], nB[8];
#pragma unroll
    for (int r = 0; r < 8; ++r) {
        const uint4* rp = (const uint4*)(Mb + ((size_t)(rbase + r) << 10));
        mA[r] = rp[lane * 2];
        mB[r] = rp[lane * 2 + 1];
        const uint4* tp = (const uint4*)(MTb + ((size_t)(rbase + r) << 10));
        nA[r] = tp[lane * 2];
        nB[r] = tp[lane * 2 + 1];
    }

    float uprev[8];
#pragma unroll
    for (int r = 0; r < 8; ++r) uprev[r] = 0.f;

    unsigned myerr = 0xffffffffu;   // tid0: this batch's fixed-point err sum for iter t

    for (int t = 0; t < MAX_ITER; ++t) {
        // ---------- u phase ----------
        {
            float4 ex;
            ex.x = fexp2(__hip_atomic_load(vb + tid * 4 + 0, __ATOMIC_RELAXED, __HIP_MEMORY_SCOPE_AGENT) * SCALE_);
            ex.y = fexp2(__hip_atomic_load(vb + tid * 4 + 1, __ATOMIC_RELAXED, __HIP_MEMORY_SCOPE_AGENT) * SCALE_);
            ex.z = fexp2(__hip_atomic_load(vb + tid * 4 + 2, __ATOMIC_RELAXED, __HIP_MEMORY_SCOPE_AGENT) * SCALE_);
            ex.w = fexp2(__hip_atomic_load(vb + tid * 4 + 3, __ATOMIC_RELAXED, __HIP_MEMORY_SCOPE_AGENT) * SCALE_);
            *(float4*)&sw[tid * 4 + 4 * (tid >> 2)] = ex;
            __syncthreads();
            float wrg[16];
            *(float4*)&wrg[0]  = *(const float4*)&sw[lane * 20 + 0];
            *(float4*)&wrg[4]  = *(const float4*)&sw[lane * 20 + 4];
            *(float4*)&wrg[8]  = *(const float4*)&sw[lane * 20 + 8];
            *(float4*)&wrg[12] = *(const float4*)&sw[lane * 20 + 12];
            float del = 0.f;
#pragma unroll
            for (int rr = 0; rr < 8; ++rr) {
                float s0 = 0.f, s1 = 0.f;
                ACC8(mA[rr], 0)
                ACC8(mB[rr], 8)
                float s = wave_sum64(s0 + s1);
                float un = eln - EPSLN2_ * flog2(s);
                del += fabsf(un - uprev[rr]);
                uprev[rr] = un;
                if (lane == 0)
                    __hip_atomic_store(ub + rbase + rr, un, __ATOMIC_RELAXED, __HIP_MEMORY_SCOPE_AGENT);
            }
            if (lane == 0) sdel[w] = del;
            asm volatile("s_waitcnt vmcnt(0)" ::: "memory");
            __syncthreads();
            if (tid == 0) {
                float dsum = sdel[0] + sdel[1] + sdel[2] + sdel[3];
                // ceil-rounded fixed point (2^-20 units), per-block saturated so the
                // 32-block batch sum can never carry into the count bits
                unsigned dfx = (unsigned)fminf(dsum * 1048576.0f, 6.0e7f) + 1u;
                unsigned long long* c = cnt64 + CNT64IDX(2 * t, b);
                unsigned long long tot =
                    __hip_atomic_fetch_add(c, (1ULL << 32) | (unsigned long long)dfx,
                                           __ATOMIC_RELAXED, __HIP_MEMORY_SCOPE_AGENT) +
                    ((1ULL << 32) | (unsigned long long)dfx);
                while ((unsigned)(tot >> 32) < NPER) {
                    __builtin_amdgcn_s_sleep(1);
                    tot = __hip_atomic_load(c, __ATOMIC_RELAXED, __HIP_MEMORY_SCOPE_AGENT);
                }
                myerr = (unsigned)tot;   // final once count==NPER; reused in v phase for free
            }
            __syncthreads();
        }
        // ---------- v phase ----------
        {
            float4 ex;
            ex.x = fexp2(__hip_atomic_load(ub + tid * 4 + 0, __ATOMIC_RELAXED, __HIP_MEMORY_SCOPE_AGENT) * SCALE_);
            ex.y = fexp2(__hip_atomic_load(ub + tid * 4 + 1, __ATOMIC_RELAXED, __HIP_MEMORY_SCOPE_AGENT) * SCALE_);
            ex.z = fexp2(__hip_atomic_load(ub + tid * 4 + 2, __ATOMIC_RELAXED, __HIP_MEMORY_SCOPE_AGENT) * SCALE_);
            ex.w = fexp2(__hip_atomic_load(ub + tid * 4 + 3, __ATOMIC_RELAXED, __HIP_MEMORY_SCOPE_AGENT) * SCALE_);
            *(float4*)&sw[tid * 4 + 4 * (tid >> 2)] = ex;
            __syncthreads();
            float wrg[16];
            *(float4*)&wrg[0]  = *(const float4*)&sw[lane * 20 + 0];
            *(float4*)&wrg[4]  = *(const float4*)&sw[lane * 20 + 4];
            *(float4*)&wrg[8]  = *(const float4*)&sw[lane * 20 + 8];
            *(float4*)&wrg[12] = *(const float4*)&sw[lane * 20 + 12];
#pragma unroll
            for (int rr = 0; rr < 8; ++rr) {
                float s0 = 0.f, s1 = 0.f;
                ACC8(nA[rr], 0)
                ACC8(nB[rr], 8)
                float s = wave_sum64(s0 + s1);
                float vn = eln - EPSLN2_ * flog2(s);
                if (lane == 0)
                    __hip_atomic_store(vb + rbase + rr, vn, __ATOMIC_RELAXED, __HIP_MEMORY_SCOPE_AGENT);
            }
            asm volatile("s_waitcnt vmcnt(0)" ::: "memory");
            __syncthreads();
            if (tid == 0) {
                unsigned long long* c = cnt64 + CNT64IDX(2 * t + 1, b);
                unsigned long long tot =
                    __hip_atomic_fetch_add(c, 1ULL << 32, __ATOMIC_RELAXED, __HIP_MEMORY_SCOPE_AGENT) +
                    (1ULL << 32);
                while ((unsigned)(tot >> 32) < NPER) {
                    __builtin_amdgcn_s_sleep(1);
                    tot = __hip_atomic_load(c, __ATOMIC_RELAXED, __HIP_MEMORY_SCOPE_AGENT);
                }
                int brk = 0;
                if (myerr < ERR_FX_THRESH) {
                    // rare path: all batches are provably at iteration t (none can break
                    // before the global sum crosses threshold), so their u-phase counters
                    // will reach NPER — no deadlock.
                    unsigned long long s = 0;
                    for (int bb = 0; bb < 8; ++bb) {
                        unsigned long long tv = __hip_atomic_load(cnt64 + CNT64IDX(2 * t, bb),
                                                                  __ATOMIC_RELAXED, __HIP_MEMORY_SCOPE_AGENT);
                        while ((unsigned)(tv >> 32) < NPER) {
                            __builtin_amdgcn_s_sleep(1);
                            tv = __hip_atomic_load(cnt64 + CNT64IDX(2 * t, bb),
                                                   __ATOMIC_RELAXED, __HIP_MEMORY_SCOPE_AGENT);
                        }
                        s += (unsigned long long)(unsigned)tv;
                    }
                    brk = (s < (unsigned long long)ERR_FX_THRESH);
                }
                sflag = brk;
            }
            __syncthreads();
            if (sflag) break;
        }
    }
}

// ---------------- WT precompute: WT[b][d][j] = bf16( exp2(v_j*S) * V[b][j][d] ) ----------------
__global__ __launch_bounds__(256) void wt_kernel(const float* __restrict__ V,
                                                 const float* __restrict__ v,
                                                 unsigned short* __restrict__ WT) {
    __shared__ __align__(16) float Vs[64][65];
    __shared__ float wj[64];
    int b = blockIdx.x & 7, jt = blockIdx.x >> 3;
    int j0 = jt * 64;
    int tid = threadIdx.x;
    const float* Vb = V + ((size_t)b << 16) + ((size_t)j0 << 6);
#pragma unroll
    for (int c = 0; c < 4; ++c) {
        int idx = tid + 256 * c;
        int row = idx >> 4, c4 = idx & 15;
        float4 x = ((const float4*)(Vb + row * 64))[c4];
        Vs[row][c4 * 4 + 0] = x.x; Vs[row][c4 * 4 + 1] = x.y;
        Vs[row][c4 * 4 + 2] = x.z; Vs[row][c4 * 4 + 3] = x.w;
    }
    if (tid < 64) wj[tid] = fexp2(v[(b << 10) + j0 + tid] * SCALE_);
    __syncthreads();
    int d = tid >> 2, qd = tid & 3;
    unsigned pk[8];
#pragma unroll
    for (int p = 0; p < 8; ++p) {
        int j = qd * 16 + p * 2;
        unsigned lo = bf16rne(Vs[j][d] * wj[j]);
        unsigned hi = bf16rne(Vs[j + 1][d] * wj[j + 1]);
        pk[p] = lo | (hi << 16);
    }
    unsigned short* dst = WT + ((size_t)b << 16) + ((size_t)d << 10) + j0 + qd * 16;
    ((uint4*)dst)[0] = make_uint4(pk[0], pk[1], pk[2], pk[3]);
    ((uint4*)dst)[1] = make_uint4(pk[4], pk[5], pk[6], pk[7]);
}

// ---------------- MFMA epilogue: out = diag(a) * (M @ W) + V ----------------
__global__ __launch_bounds__(256) void gemm_final(const unsigned short* __restrict__ M,
                                                  const unsigned short* __restrict__ WT,
                                                  const float* __restrict__ u,
                                                  const float* __restrict__ V,
                                                  float* __restrict__ out) {
    __shared__ float sa[32];
    int tid = threadIdx.x;
    int w = tid >> 6, lane = tid & 63;
    int b = blockIdx.x & 7, mt = blockIdx.x >> 3;
    if (tid < 32) sa[tid] = fexp2(u[(b << 10) + mt * 32 + tid] * SCALE_);
    __syncthreads();
    int m = lane & 15, q = lane >> 4;
    int rloc = (w & 1) * 16;
    int nbase = (w >> 1) * 32;
    const unsigned short* Ma = M + ((size_t)b << 20) + ((size_t)(mt * 32 + rloc + m) << 10) + q * 8;
    const unsigned short* W0 = WT + ((size_t)b << 16) + ((size_t)(nbase + m) << 10) + q * 8;
    const unsigned short* W1 = W0 + (16 << 10);
    f32x4 acc0 = {0.f, 0.f, 0.f, 0.f}, acc1 = {0.f, 0.f, 0.f, 0.f};
#pragma unroll 4
    for (int k0 = 0; k0 < NN; k0 += 32) {
        short8 af = *(const short8*)(Ma + k0);
        short8 b0 = *(const short8*)(W0 + k0);
        short8 b1 = *(const short8*)(W1 + k0);
        acc0 = __builtin_amdgcn_mfma_f32_16x16x32_bf16(af, b0, acc0, 0, 0, 0);
        acc1 = __builtin_amdgcn_mfma_f32_16x16x32_bf16(af, b1, acc1, 0, 0, 0);
    }
#pragma unroll
    for (int r = 0; r < 4; ++r) {
        int lrow = rloc + q * 4 + r;
        int gm = mt * 32 + lrow;
        float a = sa[lrow];
        size_t base = (((size_t)b << 10) + gm) * DD;
        int n0 = nbase + m;
        out[base + n0]      = fmaf(a, acc0[r], V[base + n0]);
        out[base + n0 + 16] = fmaf(a, acc1[r], V[base + n0 + 16]);
    }
}

extern "C" void kernel_launch(void* const* d_in, const int* in_sizes, int n_in,
                              void* d_out, int out_size, void* d_ws, size_t ws_size,
                              hipStream_t stream) {
    const float* q = (const float*)d_in[0];
    const float* k = (const float*)d_in[1];
    const float* V = (const float*)d_in[2];
    float* out = (float*)d_out;

    char* ws = (char*)d_ws;
    const size_t MB16 = (size_t)BB * NN * NN * sizeof(unsigned short);   // 16 MB
    unsigned short* M  = (unsigned short*)ws;
    unsigned short* MT = (unsigned short*)(ws + MB16);
    unsigned short* WT = MT;                  // MT is dead after sink; reuse (1 MB)
    float* u   = (float*)(ws + 2 * MB16);
    float* v   = u + BB * NN;                               // u+v = 64 KiB
    unsigned long long* cnt64 = (unsigned long long*)(v + BB * NN);   // 1600 u64 = 12,800 B

    // u, v, cnt64 contiguous: 65,536 + 12,800 = 78,336 B (exactly the R3-proven bound)
    size_t zbytes = (size_t)(2 * BB * NN) * 4 + 1600 * 8;
    hipMemsetAsync(u, 0, zbytes, stream);

    cost_kernel<<<dim3(16, 16, 8), 256, 0, stream>>>(q, k, M, MT);

    float eln = EPSF * logf(1.0f / NN + 1e-8f);
    // REGULAR launch: barrier is hand-rolled, co-residency is de-facto guaranteed at
    // 256 blocks / 256 CUs (128 VGPR, 5.6KB LDS). Failure mode if placement ever
    // splits: visible hang, not silent corruption.
    sink_coop<<<dim3(NBLK), dim3(256), 0, stream>>>(M, MT, u, v, cnt64, eln);

    wt_kernel<<<128, 256, 0, stream>>>(V, v, WT);
    gemm_final<<<256, 256, 0, stream>>>(M, WT, u, V, out);
}